// Round 2
// baseline (189.062 us; speedup 1.0000x reference)
//
#include <hip/hip_runtime.h>

#define BB 8
#define NN 128
#define ND 64
#define LL 512
#define RD 1024
#define CG 128
#define CP 128
#define HID 192

// ---------------------------------------------------------------------------
// K1: blocks 0..255:  h0 = nodes @ Wn + bn ; norm = rsqrt(max(deg,1))
//     block  256:     v = W2@Wo, bc = br@W1b, cconst = N*L*(b2@Wo)+bo, acc=0
//     blocks 257..512: Wc = Wr @ W1b   [1024 x 192]  (4 Wr-rows per block)
// grid 513 x 256
// ---------------------------------------------------------------------------
__global__ __launch_bounds__(256) void k1_h0_norm_prep(
    const float* __restrict__ adj, const float* __restrict__ nodes,
    const float* __restrict__ Wn, const float* __restrict__ bn,
    const float* __restrict__ Wr, const float* __restrict__ br,
    const float* __restrict__ W1,
    const float* __restrict__ W2, const float* __restrict__ b2,
    const float* __restrict__ Wo, const float* __restrict__ bo,
    float* __restrict__ hA, float* __restrict__ normb,
    float* __restrict__ vbuf, float* __restrict__ cconst,
    float* __restrict__ acc, float* __restrict__ Wc, float* __restrict__ bc)
{
    int t = threadIdx.x;
    int blk = blockIdx.x;
    const float* W1b = W1 + CG * HID;
    if (blk == 256) {
        if (t < HID) {
            float s = 0.f;
            for (int k = 0; k < CG; ++k) s = fmaf(W2[t * CG + k], Wo[k], s);
            vbuf[t] = s;
            float sb = 0.f;
            for (int m = 0; m < CG; ++m) sb = fmaf(br[m], W1b[m * HID + t], sb);
            bc[t] = sb;
        }
        if (t == 255) {
            float s = 0.f;
            for (int k = 0; k < CG; ++k) s = fmaf(b2[k], Wo[k], s);
            cconst[0] = (float)(NN * LL) * s + bo[0];
        }
        if (t < BB) acc[t] = 0.f;
        return;
    }
    if (blk > 256) {
        // Wc block: 4 rows of Wr
        int r0 = (blk - 257) * 4;
        __shared__ float sW[4][CG];
        if (t < 128) ((float4*)&sW[0][0])[t] = ((const float4*)(Wr + (size_t)r0 * CG))[t];
        __syncthreads();
        #pragma unroll
        for (int q = 0; q < 3; ++q) {
            int o = q * 256 + t;            // 0..767
            int r = o / HID, c = o % HID;
            float s = 0.f;
            for (int m = 0; m < CG; ++m) s = fmaf(sW[r][m], W1b[m * HID + c], s);
            Wc[(size_t)(r0 + r) * HID + c] = s;
        }
        return;
    }
    int b = blk >> 5;           // 32 blocks per batch
    int n0 = (blk & 31) * 4;    // 4 rows per block
    __shared__ float sn[4][ND];
    sn[t >> 6][t & 63] = nodes[(b * NN + n0 + (t >> 6)) * ND + (t & 63)];
    __syncthreads();
    {
        int w = t >> 6, lane = t & 63;
        const float* ar = adj + (size_t)(b * NN + n0 + w) * NN;
        float d = ar[lane] + ar[lane + 64];
        for (int off = 32; off; off >>= 1) d += __shfl_down(d, off);
        if (lane == 0) normb[b * NN + n0 + w] = rsqrtf(fmaxf(d, 1.0f));
    }
    int c = t & 127, rr = t >> 7;   // rows rr and rr+2
    float a0 = bn[c], a1 = bn[c];
    for (int k = 0; k < ND; ++k) {
        float wv = Wn[k * CG + c];
        a0 = fmaf(sn[rr][k], wv, a0);
        a1 = fmaf(sn[rr + 2][k], wv, a1);
    }
    hA[(b * NN + n0 + rr) * CG + c] = a0;
    hA[(b * NN + n0 + rr + 2) * CG + c] = a1;
}

// ---------------------------------------------------------------------------
// K2: one GNN step: hnew = act( (adj @ (h*norm)) * norm @ Wg + bg )
// MODE 0: relu, store hout. MODE 1: tanh, then hW1 = h @ W1_top + b1.
// grid B*32 (4 rows/block) x 256
// ---------------------------------------------------------------------------
template <int MODE>
__global__ __launch_bounds__(256) void k2_gnn(
    const float* __restrict__ adj, const float* __restrict__ hin,
    const float* __restrict__ Wg, const float* __restrict__ bg,
    const float* __restrict__ normb, float* __restrict__ hout,
    const float* __restrict__ W1, const float* __restrict__ b1,
    float* __restrict__ hW1)
{
    int t = threadIdx.x;
    int b = blockIdx.x >> 5;
    int i0 = (blockIdx.x & 31) * 4;
    __shared__ float hs[64][CG];    // 32KB
    __shared__ float ms[4][CG];
    int c = t & 127;
    int ib = (t >> 7) * 2;          // 0 or 2
    float m[2] = {0.f, 0.f};
    const float* hbase = hin + (size_t)b * NN * CG;
    for (int half = 0; half < 2; ++half) {
        __syncthreads();
        #pragma unroll
        for (int q = 0; q < 8; ++q) {
            int f4 = t + 256 * q;        // 0..2047
            int row = f4 >> 5;           // 0..63
            int col4 = (f4 & 31) * 4;
            float4 hv = *(const float4*)(hbase + (half * 64 + row) * CG + col4);
            float nv = normb[b * NN + half * 64 + row];
            hv.x *= nv; hv.y *= nv; hv.z *= nv; hv.w *= nv;
            *(float4*)(&hs[row][col4]) = hv;
        }
        __syncthreads();
        const float* arow = adj + (size_t)(b * NN + i0 + ib) * NN + half * 64;
        for (int j = 0; j < 64; ++j) {
            float hv = hs[j][c];
            m[0] = fmaf(arow[j], hv, m[0]);
            m[1] = fmaf(arow[NN + j], hv, m[1]);
        }
    }
    #pragma unroll
    for (int k = 0; k < 2; ++k)
        ms[ib + k][c] = m[k] * normb[b * NN + i0 + ib + k];
    __syncthreads();
    float acc2[2];
    acc2[0] = bg[c]; acc2[1] = bg[c];
    for (int k = 0; k < CG; ++k) {
        float wv = Wg[k * CG + c];
        acc2[0] = fmaf(ms[ib + 0][k], wv, acc2[0]);
        acc2[1] = fmaf(ms[ib + 1][k], wv, acc2[1]);
    }
    if (MODE == 0) {
        #pragma unroll
        for (int k = 0; k < 2; ++k)
            hout[(size_t)(b * NN + i0 + ib + k) * CG + c] = fmaxf(acc2[k], 0.f);
    } else {
        float* hn = &hs[0][0];   // reuse (4*128 floats)
        #pragma unroll
        for (int k = 0; k < 2; ++k)
            hn[(ib + k) * CG + c] = tanhf(acc2[k]);
        __syncthreads();
        // hW1: 4 rows x 192 = 768 outputs, 3 per thread; b1 folded here
        #pragma unroll
        for (int q = 0; q < 3; ++q) {
            int out = t + 256 * q;
            int i = out / HID, jj = out % HID;
            float s = b1[jj];
            for (int k = 0; k < CG; ++k)
                s = fmaf(hn[i * CG + k], W1[k * HID + jj], s);
            hW1[(size_t)(b * NN + i0 + i) * HID + jj] = s;
        }
    }
}

// ---------------------------------------------------------------------------
// K3: rW1[4096][192] = prot[4096][1024] @ Wc[1024][192] + bc
// tile 16 rows x 64 cols, grid 768 (256 rowblocks x 3 colchunks) x 256
// ---------------------------------------------------------------------------
#define KC 256
#define SPLD 260
__global__ __launch_bounds__(256) void k3_gemm(
    const float* __restrict__ prot, const float* __restrict__ Wc,
    const float* __restrict__ bc, float* __restrict__ rW1)
{
    int t = threadIdx.x;
    int rb = blockIdx.x / 3;
    int cc = blockIdx.x % 3;
    int ty = t >> 4;                 // row 0..15
    int tx = t & 15;                 // col quad 0..15
    int col4 = cc * 64 + tx * 4;
    __shared__ float sp[16 * SPLD];  // 16.6 KB, padded stride
    float4 a = {0.f, 0.f, 0.f, 0.f};
    const float* spr = sp + ty * SPLD;
    for (int k0 = 0; k0 < RD; k0 += KC) {
        __syncthreads();
        #pragma unroll
        for (int q = 0; q < 4; ++q) {
            int f = t + 256 * q;         // 0..1023
            int row = f >> 6;            // 0..15
            int c4 = (f & 63) * 4;       // 0..252
            float4 pv = *(const float4*)(prot + (size_t)(rb * 16 + row) * RD + k0 + c4);
            *(float4*)(&sp[row * SPLD + c4]) = pv;
        }
        __syncthreads();
        #pragma unroll 4
        for (int kk4 = 0; kk4 < KC / 4; ++kk4) {
            float4 p = *(const float4*)(spr + kk4 * 4);
            const float* wb = Wc + (size_t)(k0 + kk4 * 4) * HID + col4;
            float4 w0 = *(const float4*)(wb);
            float4 w1 = *(const float4*)(wb + HID);
            float4 w2 = *(const float4*)(wb + 2 * HID);
            float4 w3 = *(const float4*)(wb + 3 * HID);
            a.x = fmaf(p.x, w0.x, a.x); a.y = fmaf(p.x, w0.y, a.y);
            a.z = fmaf(p.x, w0.z, a.z); a.w = fmaf(p.x, w0.w, a.w);
            a.x = fmaf(p.y, w1.x, a.x); a.y = fmaf(p.y, w1.y, a.y);
            a.z = fmaf(p.y, w1.z, a.z); a.w = fmaf(p.y, w1.w, a.w);
            a.x = fmaf(p.z, w2.x, a.x); a.y = fmaf(p.z, w2.y, a.y);
            a.z = fmaf(p.z, w2.z, a.z); a.w = fmaf(p.z, w2.w, a.w);
            a.x = fmaf(p.w, w3.x, a.x); a.y = fmaf(p.w, w3.y, a.y);
            a.z = fmaf(p.w, w3.z, a.z); a.w = fmaf(p.w, w3.w, a.w);
        }
    }
    float4 bv = *(const float4*)(bc + col4);
    a.x += bv.x; a.y += bv.y; a.z += bv.z; a.w += bv.w;
    *(float4*)(rW1 + (size_t)(rb * 16 + ty) * HID + col4) = a;
}

// ---------------------------------------------------------------------------
// K4: acc[b] += sum_{n,l} v . relu(hW1[b,n,:] + rW1[b,l,:])
// grid B*8(nsplit)*8(ltile) = 512 x 256 ; wave owns j-quarter, lane owns l
// ---------------------------------------------------------------------------
__global__ __launch_bounds__(256) void k4_pairsum(
    const float* __restrict__ hW1, const float* __restrict__ rW1,
    const float* __restrict__ vbuf, float* __restrict__ acc)
{
    int t = threadIdx.x;
    int blk = blockIdx.x;
    int b = blk >> 6;
    int ns = (blk >> 3) & 7;    // n range: 16 rows
    int lt = blk & 7;           // l tile: 64
    int wv = t >> 6;            // j-quarter (48 dims)
    int lane = t & 63;
    int j0 = wv * 48;
    int l = lt * 64 + lane;
    float r[48], v[48];
    const float* rp = rW1 + ((size_t)b * LL + l) * HID + j0;
    const float* vp = vbuf + j0;
    #pragma unroll
    for (int q = 0; q < 12; ++q) {
        float4 f = *(const float4*)(rp + q * 4);
        r[q * 4 + 0] = f.x; r[q * 4 + 1] = f.y; r[q * 4 + 2] = f.z; r[q * 4 + 3] = f.w;
    }
    #pragma unroll
    for (int q = 0; q < 12; ++q) {
        float4 f = *(const float4*)(vp + q * 4);
        v[q * 4 + 0] = f.x; v[q * 4 + 1] = f.y; v[q * 4 + 2] = f.z; v[q * 4 + 3] = f.w;
    }
    float a0 = 0.f, a1 = 0.f, a2 = 0.f, a3 = 0.f;
    const float* hp = hW1 + ((size_t)b * NN + ns * 16) * HID + j0;
    for (int n = 0; n < 16; ++n) {
        float hv[48];
        #pragma unroll
        for (int q = 0; q < 12; ++q) {
            float4 f = *(const float4*)(hp + n * HID + q * 4);
            hv[q * 4 + 0] = f.x; hv[q * 4 + 1] = f.y; hv[q * 4 + 2] = f.z; hv[q * 4 + 3] = f.w;
        }
        #pragma unroll
        for (int j = 0; j < 48; j += 4) {
            a0 = fmaf(v[j + 0], fmaxf(hv[j + 0] + r[j + 0], 0.f), a0);
            a1 = fmaf(v[j + 1], fmaxf(hv[j + 1] + r[j + 1], 0.f), a1);
            a2 = fmaf(v[j + 2], fmaxf(hv[j + 2] + r[j + 2], 0.f), a2);
            a3 = fmaf(v[j + 3], fmaxf(hv[j + 3] + r[j + 3], 0.f), a3);
        }
    }
    float a = (a0 + a1) + (a2 + a3);
    for (int off = 32; off; off >>= 1) a += __shfl_down(a, off);
    __shared__ float sred[4];
    if (lane == 0) sred[wv] = a;
    __syncthreads();
    if (t == 0) atomicAdd(&acc[b], (sred[0] + sred[1]) + (sred[2] + sred[3]));
}

// ---------------------------------------------------------------------------
// K5: out[b] = acc[b] + cconst
// ---------------------------------------------------------------------------
__global__ __launch_bounds__(64) void k5_final(
    const float* __restrict__ acc, const float* __restrict__ cconst,
    float* __restrict__ out)
{
    int t = threadIdx.x;
    if (t < BB) out[t] = acc[t] + cconst[0];
}

extern "C" void kernel_launch(void* const* d_in, const int* in_sizes, int n_in,
                              void* d_out, int out_size, void* d_ws, size_t ws_size,
                              hipStream_t stream)
{
    const float* adj   = (const float*)d_in[0];
    const float* nodes = (const float*)d_in[1];
    const float* prot  = (const float*)d_in[2];
    const float* Wn    = (const float*)d_in[3];
    const float* bn    = (const float*)d_in[4];
    const float* Wg    = (const float*)d_in[5];
    const float* bg    = (const float*)d_in[6];
    const float* Wr    = (const float*)d_in[7];
    const float* br    = (const float*)d_in[8];
    // d_in[9]=Wa, d_in[10]=ba: unused (softmax over size-1 axis == 1)
    const float* W1    = (const float*)d_in[11];
    const float* b1    = (const float*)d_in[12];
    const float* W2    = (const float*)d_in[13];
    const float* b2    = (const float*)d_in[14];
    const float* Wo    = (const float*)d_in[15];
    const float* bo    = (const float*)d_in[16];

    float* ws     = (float*)d_ws;
    float* hA     = ws;                       // [8][128][128]
    float* hB     = hA + BB * NN * CG;        // [8][128][128]
    float* normb  = hB + BB * NN * CG;        // [8][128]
    float* hW1b   = normb + BB * NN;          // [8][128][192]  (aliased as Wc first)
    float* rW1b   = hW1b + BB * NN * HID;     // [8][512][192]
    float* vbuf   = rW1b + BB * LL * HID;     // [192]
    float* cconst = vbuf + HID;               // [1]
    float* accb   = cconst + 1;               // [8]
    float* bc     = accb + 8;                 // [192]
    float* Wc     = hW1b;                     // [1024][192] == 8*128*192, reused
    float* out    = (float*)d_out;

    // k1 computes h0/norm + prep consts + Wc (needed by k3)
    hipLaunchKernelGGL(k1_h0_norm_prep, dim3(513), dim3(256), 0, stream,
                       adj, nodes, Wn, bn, Wr, br, W1, W2, b2, Wo, bo,
                       hA, normb, vbuf, cconst, accb, Wc, bc);
    hipLaunchKernelGGL(k3_gemm, dim3(768), dim3(256), 0, stream, prot, Wc, bc, rW1b);
    // GNN chain (hW1b region free again after k3 consumed Wc)
    hipLaunchKernelGGL(k2_gnn<0>, dim3(BB * 32), dim3(256), 0, stream,
                       adj, hA, Wg, bg, normb, hB, W1, b1, hW1b);
    hipLaunchKernelGGL(k2_gnn<0>, dim3(BB * 32), dim3(256), 0, stream,
                       adj, hB, Wg, bg, normb, hA, W1, b1, hW1b);
    hipLaunchKernelGGL(k2_gnn<1>, dim3(BB * 32), dim3(256), 0, stream,
                       adj, hA, Wg, bg, normb, hB, W1, b1, hW1b);
    hipLaunchKernelGGL(k4_pairsum, dim3(512), dim3(256), 0, stream, hW1b, rW1b, vbuf, accb);
    hipLaunchKernelGGL(k5_final, dim3(1), dim3(64), 0, stream, accb, cconst, out);
}

// Round 3
// 111.743 us; speedup vs baseline: 1.6919x; 1.6919x over previous
//
#include <hip/hip_runtime.h>

#define BB 8
#define NN 128
#define ND 64
#define LL 512
#define RD 1024
#define CG 128
#define CP 128
#define HID 192

typedef __attribute__((ext_vector_type(8))) short short8;
typedef __attribute__((ext_vector_type(4))) float f32x4;

__device__ __forceinline__ unsigned short f2bf(float x) {
    unsigned u = __builtin_bit_cast(unsigned, x);
    u += 0x7fffu + ((u >> 16) & 1u);          // RNE
    return (unsigned short)(u >> 16);
}

// ---------------------------------------------------------------------------
// K1 (grid 2561 x 256):
//  blk <256   : h0 = nodes@Wn + bn ; norm = rsqrt(max(deg,1))
//  blk ==256  : vbuf = W2@Wo ; bc = br@W1b ; cconst = N*L*(b2@Wo)+bo ; acc=0; ctr=0
//  257..512   : WcT[c][k] = bf16( (Wr@W1b)[k][c] )   (4 k-rows per block)
//  513..2560  : protb = bf16(prot)  (2048 elems per block)
// ---------------------------------------------------------------------------
__global__ __launch_bounds__(256) void k1_prep(
    const float* __restrict__ adj, const float* __restrict__ nodes,
    const float* __restrict__ prot,
    const float* __restrict__ Wn, const float* __restrict__ bn,
    const float* __restrict__ Wr, const float* __restrict__ br,
    const float* __restrict__ W1,
    const float* __restrict__ W2, const float* __restrict__ b2,
    const float* __restrict__ Wo, const float* __restrict__ bo,
    float* __restrict__ hA, float* __restrict__ normb,
    float* __restrict__ vbuf, float* __restrict__ cconst,
    float* __restrict__ acc, unsigned* __restrict__ ctr,
    unsigned short* __restrict__ WcT, float* __restrict__ bc,
    unsigned short* __restrict__ protb)
{
    int t = threadIdx.x;
    int blk = blockIdx.x;
    const float* W1b = W1 + CG * HID;
    if (blk >= 513) {
        // bf16 conversion of prot: 8 elems/thread
        size_t base = (size_t)(blk - 513) * 2048 + (size_t)t * 8;
        float4 p0 = *(const float4*)(prot + base);
        float4 p1 = *(const float4*)(prot + base + 4);
        unsigned short o[8];
        o[0] = f2bf(p0.x); o[1] = f2bf(p0.y); o[2] = f2bf(p0.z); o[3] = f2bf(p0.w);
        o[4] = f2bf(p1.x); o[5] = f2bf(p1.y); o[6] = f2bf(p1.z); o[7] = f2bf(p1.w);
        *(short8*)(protb + base) = *(const short8*)o;
        return;
    }
    if (blk == 256) {
        if (t < HID) {
            float s = 0.f;
            for (int k = 0; k < CG; ++k) s = fmaf(W2[t * CG + k], Wo[k], s);
            vbuf[t] = s;
            float sb = 0.f;
            for (int m = 0; m < CG; ++m) sb = fmaf(br[m], W1b[m * HID + t], sb);
            bc[t] = sb;
        }
        if (t == 255) {
            float s = 0.f;
            for (int k = 0; k < CG; ++k) s = fmaf(b2[k], Wo[k], s);
            cconst[0] = (float)(NN * LL) * s + bo[0];
        }
        if (t == 254) *ctr = 0u;
        if (t < BB) acc[t] = 0.f;
        return;
    }
    if (blk > 256) {
        // WcT block: 4 k-rows of Wc = Wr @ W1b, stored transposed bf16
        int r0 = (blk - 257) * 4;
        __shared__ float sW[4][CG];
        if (t < 128) ((float4*)&sW[0][0])[t] = ((const float4*)(Wr + (size_t)r0 * CG))[t];
        __syncthreads();
        #pragma unroll
        for (int q = 0; q < 3; ++q) {
            int o = q * 256 + t;            // 0..767
            int r = o / HID, c = o % HID;
            float s = 0.f;
            for (int m = 0; m < CG; ++m) s = fmaf(sW[r][m], W1b[m * HID + c], s);
            WcT[(size_t)c * RD + r0 + r] = f2bf(s);
        }
        return;
    }
    int b = blk >> 5;           // 32 blocks per batch
    int n0 = (blk & 31) * 4;    // 4 rows per block
    __shared__ float sn[4][ND];
    sn[t >> 6][t & 63] = nodes[(b * NN + n0 + (t >> 6)) * ND + (t & 63)];
    __syncthreads();
    {
        int w = t >> 6, lane = t & 63;
        const float* ar = adj + (size_t)(b * NN + n0 + w) * NN;
        float d = ar[lane] + ar[lane + 64];
        for (int off = 32; off; off >>= 1) d += __shfl_down(d, off);
        if (lane == 0) normb[b * NN + n0 + w] = rsqrtf(fmaxf(d, 1.0f));
    }
    int c = t & 127, rr = t >> 7;   // rows rr and rr+2
    float a0 = bn[c], a1 = bn[c];
    for (int k = 0; k < ND; ++k) {
        float wv = Wn[k * CG + c];
        a0 = fmaf(sn[rr][k], wv, a0);
        a1 = fmaf(sn[rr + 2][k], wv, a1);
    }
    hA[(b * NN + n0 + rr) * CG + c] = a0;
    hA[(b * NN + n0 + rr + 2) * CG + c] = a1;
}

// ---------------------------------------------------------------------------
// K2: one GNN step: hnew = act( (adj @ (h*norm)) * norm @ Wg + bg )
// MODE 0: relu, store hout. MODE 1: tanh, then hW1 = h @ W1_top + b1.
// grid B*32 (4 rows/block) x 256
// ---------------------------------------------------------------------------
template <int MODE>
__global__ __launch_bounds__(256) void k2_gnn(
    const float* __restrict__ adj, const float* __restrict__ hin,
    const float* __restrict__ Wg, const float* __restrict__ bg,
    const float* __restrict__ normb, float* __restrict__ hout,
    const float* __restrict__ W1, const float* __restrict__ b1,
    float* __restrict__ hW1)
{
    int t = threadIdx.x;
    int b = blockIdx.x >> 5;
    int i0 = (blockIdx.x & 31) * 4;
    __shared__ float hs[64][CG];    // 32KB
    __shared__ float ms[4][CG];
    int c = t & 127;
    int ib = (t >> 7) * 2;          // 0 or 2
    float m[2] = {0.f, 0.f};
    const float* hbase = hin + (size_t)b * NN * CG;
    for (int half = 0; half < 2; ++half) {
        __syncthreads();
        #pragma unroll
        for (int q = 0; q < 8; ++q) {
            int f4 = t + 256 * q;        // 0..2047
            int row = f4 >> 5;           // 0..63
            int col4 = (f4 & 31) * 4;
            float4 hv = *(const float4*)(hbase + (half * 64 + row) * CG + col4);
            float nv = normb[b * NN + half * 64 + row];
            hv.x *= nv; hv.y *= nv; hv.z *= nv; hv.w *= nv;
            *(float4*)(&hs[row][col4]) = hv;
        }
        __syncthreads();
        const float* arow = adj + (size_t)(b * NN + i0 + ib) * NN + half * 64;
        for (int j = 0; j < 64; ++j) {
            float hv = hs[j][c];
            m[0] = fmaf(arow[j], hv, m[0]);
            m[1] = fmaf(arow[NN + j], hv, m[1]);
        }
    }
    #pragma unroll
    for (int k = 0; k < 2; ++k)
        ms[ib + k][c] = m[k] * normb[b * NN + i0 + ib + k];
    __syncthreads();
    float acc2[2];
    acc2[0] = bg[c]; acc2[1] = bg[c];
    for (int k = 0; k < CG; ++k) {
        float wv = Wg[k * CG + c];
        acc2[0] = fmaf(ms[ib + 0][k], wv, acc2[0]);
        acc2[1] = fmaf(ms[ib + 1][k], wv, acc2[1]);
    }
    if (MODE == 0) {
        #pragma unroll
        for (int k = 0; k < 2; ++k)
            hout[(size_t)(b * NN + i0 + ib + k) * CG + c] = fmaxf(acc2[k], 0.f);
    } else {
        float* hn = &hs[0][0];   // reuse (4*128 floats)
        #pragma unroll
        for (int k = 0; k < 2; ++k)
            hn[(ib + k) * CG + c] = tanhf(acc2[k]);
        __syncthreads();
        // hW1: 4 rows x 192 = 768 outputs, 3 per thread; b1 folded here
        #pragma unroll
        for (int q = 0; q < 3; ++q) {
            int out = t + 256 * q;
            int i = out / HID, jj = out % HID;
            float s = b1[jj];
            for (int k = 0; k < CG; ++k)
                s = fmaf(hn[i * CG + k], W1[k * HID + jj], s);
            hW1[(size_t)(b * NN + i0 + i) * HID + jj] = s;
        }
    }
}

// ---------------------------------------------------------------------------
// K3: rW1[4096][192] = protb[4096][1024](bf16) @ WcT^T(bf16) + bc  via MFMA
// block = 256 thr (4 waves); wave owns 16 rows x 48 cols (3 mfma col-tiles)
// grid = (4096/64) x (192/48) = 256 blocks
// ---------------------------------------------------------------------------
__global__ __launch_bounds__(256) void k3_mfma(
    const unsigned short* __restrict__ protb, const unsigned short* __restrict__ WcT,
    const float* __restrict__ bc, float* __restrict__ rW1)
{
    int t = threadIdx.x;
    int w = t >> 6, l = t & 63;
    int rb = blockIdx.x >> 2;
    int cb = blockIdx.x & 3;
    int r0 = rb * 64 + w * 16;
    int c0 = cb * 48;
    int lr = l & 15;
    int lk = (l >> 4) * 8;
    const unsigned short* ap = protb + (size_t)(r0 + lr) * RD + lk;
    const unsigned short* bp = WcT + (size_t)(c0 + lr) * RD + lk;
    f32x4 a0 = {0.f, 0.f, 0.f, 0.f}, a1 = a0, a2 = a0;
    #pragma unroll 4
    for (int k0 = 0; k0 < RD; k0 += 32) {
        short8 av = *(const short8*)(ap + k0);
        short8 b0 = *(const short8*)(bp + k0);
        short8 b1 = *(const short8*)(bp + 16 * RD + k0);
        short8 b2 = *(const short8*)(bp + 32 * RD + k0);
        a0 = __builtin_amdgcn_mfma_f32_16x16x32_bf16(av, b0, a0, 0, 0, 0);
        a1 = __builtin_amdgcn_mfma_f32_16x16x32_bf16(av, b1, a1, 0, 0, 0);
        a2 = __builtin_amdgcn_mfma_f32_16x16x32_bf16(av, b2, a2, 0, 0, 0);
    }
    int orow = r0 + (l >> 4) * 4;
    float bc0 = bc[c0 + lr], bc1 = bc[c0 + 16 + lr], bc2 = bc[c0 + 32 + lr];
    #pragma unroll
    for (int i = 0; i < 4; ++i) {
        float* cr = rW1 + (size_t)(orow + i) * HID + c0 + lr;
        cr[0]  = a0[i] + bc0;
        cr[16] = a1[i] + bc1;
        cr[32] = a2[i] + bc2;
    }
}

// ---------------------------------------------------------------------------
// K4: acc[b] += sum_{n,l} v . relu(hW1[b,n,:] + rW1[b,l,:]) ; last block
//     writes out[b] = acc[b] + cconst.
// grid B*8(nsplit)*8(ltile) = 512 x 256
// ---------------------------------------------------------------------------
__global__ __launch_bounds__(256) void k4_pairsum(
    const float* __restrict__ hW1, const float* __restrict__ rW1,
    const float* __restrict__ vbuf, float* __restrict__ acc,
    const float* __restrict__ cconst, unsigned* __restrict__ ctr,
    float* __restrict__ out)
{
    int t = threadIdx.x;
    int blk = blockIdx.x;
    int b = blk >> 6;
    int ns = (blk >> 3) & 7;    // n range: 16 rows
    int lt = blk & 7;           // l tile: 64
    int wv = t >> 6;            // j-quarter (48 dims)
    int lane = t & 63;
    int j0 = wv * 48;
    int l = lt * 64 + lane;
    float r[48], v[48];
    const float* rp = rW1 + ((size_t)b * LL + l) * HID + j0;
    const float* vp = vbuf + j0;
    #pragma unroll
    for (int q = 0; q < 12; ++q) {
        float4 f = *(const float4*)(rp + q * 4);
        r[q * 4 + 0] = f.x; r[q * 4 + 1] = f.y; r[q * 4 + 2] = f.z; r[q * 4 + 3] = f.w;
    }
    #pragma unroll
    for (int q = 0; q < 12; ++q) {
        float4 f = *(const float4*)(vp + q * 4);
        v[q * 4 + 0] = f.x; v[q * 4 + 1] = f.y; v[q * 4 + 2] = f.z; v[q * 4 + 3] = f.w;
    }
    float a0 = 0.f, a1 = 0.f, a2 = 0.f, a3 = 0.f;
    const float* hp = hW1 + ((size_t)b * NN + ns * 16) * HID + j0;
    for (int n = 0; n < 16; ++n) {
        float hv[48];
        #pragma unroll
        for (int q = 0; q < 12; ++q) {
            float4 f = *(const float4*)(hp + n * HID + q * 4);
            hv[q * 4 + 0] = f.x; hv[q * 4 + 1] = f.y; hv[q * 4 + 2] = f.z; hv[q * 4 + 3] = f.w;
        }
        #pragma unroll
        for (int j = 0; j < 48; j += 4) {
            a0 = fmaf(v[j + 0], fmaxf(hv[j + 0] + r[j + 0], 0.f), a0);
            a1 = fmaf(v[j + 1], fmaxf(hv[j + 1] + r[j + 1], 0.f), a1);
            a2 = fmaf(v[j + 2], fmaxf(hv[j + 2] + r[j + 2], 0.f), a2);
            a3 = fmaf(v[j + 3], fmaxf(hv[j + 3] + r[j + 3], 0.f), a3);
        }
    }
    float a = (a0 + a1) + (a2 + a3);
    for (int off = 32; off; off >>= 1) a += __shfl_down(a, off);
    __shared__ float sred[4];
    __shared__ int lastf;
    if (lane == 0) sred[wv] = a;
    __syncthreads();
    if (t == 0) {
        atomicAdd(&acc[b], (sred[0] + sred[1]) + (sred[2] + sred[3]));
        __threadfence();
        unsigned old = atomicAdd(ctr, 1u);
        lastf = (old == gridDim.x - 1) ? 1 : 0;
    }
    __syncthreads();
    if (lastf && t < BB)
        out[t] = atomicAdd(&acc[t], 0.0f) + cconst[0];
}

extern "C" void kernel_launch(void* const* d_in, const int* in_sizes, int n_in,
                              void* d_out, int out_size, void* d_ws, size_t ws_size,
                              hipStream_t stream)
{
    const float* adj   = (const float*)d_in[0];
    const float* nodes = (const float*)d_in[1];
    const float* prot  = (const float*)d_in[2];
    const float* Wn    = (const float*)d_in[3];
    const float* bn    = (const float*)d_in[4];
    const float* Wg    = (const float*)d_in[5];
    const float* bg    = (const float*)d_in[6];
    const float* Wr    = (const float*)d_in[7];
    const float* br    = (const float*)d_in[8];
    // d_in[9]=Wa, d_in[10]=ba: unused (softmax over size-1 axis == 1)
    const float* W1    = (const float*)d_in[11];
    const float* b1    = (const float*)d_in[12];
    const float* W2    = (const float*)d_in[13];
    const float* b2    = (const float*)d_in[14];
    const float* Wo    = (const float*)d_in[15];
    const float* bo    = (const float*)d_in[16];

    float* ws     = (float*)d_ws;
    float* hA     = ws;                        // [8][128][128]        @0
    float* hB     = ws + 131072;               // [8][128][128]
    float* normb  = ws + 262144;               // [8][128]
    float* hW1b   = ws + 263168;               // [8][128][192]
    float* rW1b   = ws + 459776;               // [8][512][192]
    float* vbuf   = ws + 1246208;              // [192]
    float* cconst = ws + 1246400;              // [1]
    float* accb   = ws + 1246404;              // [8]
    float* bc     = ws + 1246412;              // [192]
    unsigned* ctr = (unsigned*)(ws + 1246604); // [1]
    unsigned short* protb = (unsigned short*)(ws + 1246608); // [4096][1024] bf16
    unsigned short* WcT   = (unsigned short*)(ws + 3343760); // [192][1024] bf16
    float* out    = (float*)d_out;

    hipLaunchKernelGGL(k1_prep, dim3(2561), dim3(256), 0, stream,
                       adj, nodes, prot, Wn, bn, Wr, br, W1, W2, b2, Wo, bo,
                       hA, normb, vbuf, cconst, accb, ctr, WcT, bc, protb);
    hipLaunchKernelGGL(k3_mfma, dim3(256), dim3(256), 0, stream, protb, WcT, bc, rW1b);
    hipLaunchKernelGGL(k2_gnn<0>, dim3(BB * 32), dim3(256), 0, stream,
                       adj, hA, Wg, bg, normb, hB, W1, b1, hW1b);
    hipLaunchKernelGGL(k2_gnn<0>, dim3(BB * 32), dim3(256), 0, stream,
                       adj, hB, Wg, bg, normb, hA, W1, b1, hW1b);
    hipLaunchKernelGGL(k2_gnn<1>, dim3(BB * 32), dim3(256), 0, stream,
                       adj, hA, Wg, bg, normb, hB, W1, b1, hW1b);
    hipLaunchKernelGGL(k4_pairsum, dim3(512), dim3(256), 0, stream,
                       hW1b, rW1b, vbuf, accb, cconst, ctr, out);
}

// Round 4
// 102.501 us; speedup vs baseline: 1.8445x; 1.0902x over previous
//
#include <hip/hip_runtime.h>

#define BB 8
#define NN 128
#define ND 64
#define LL 512
#define RD 1024
#define CG 128
#define CP 128
#define HID 192

typedef __attribute__((ext_vector_type(8))) short short8;
typedef __attribute__((ext_vector_type(4))) float f32x4;

__device__ __forceinline__ unsigned short f2bf(float x) {
    unsigned u = __builtin_bit_cast(unsigned, x);
    u += 0x7fffu + ((u >> 16) & 1u);          // RNE
    return (unsigned short)(u >> 16);
}

// ---------------------------------------------------------------------------
// K1 (grid 2561 x 256):
//  blk <256   : h0 = nodes@Wn + bn ; norm = rsqrt(max(deg,1))
//  blk ==256  : vbuf = W2@Wo ; b1c = b1 + br@W1b ; cconst ; acc=0 ; ctr=0
//  257..512   : WcT[c][k] = bf16( (Wr@W1b)[k][c] )   (4 k-rows per block)
//  513..2560  : protb = bf16(prot)  (2048 elems per block)
// ---------------------------------------------------------------------------
__global__ __launch_bounds__(256) void k1_prep(
    const float* __restrict__ adj, const float* __restrict__ nodes,
    const float* __restrict__ prot,
    const float* __restrict__ Wn, const float* __restrict__ bn,
    const float* __restrict__ Wr, const float* __restrict__ br,
    const float* __restrict__ W1, const float* __restrict__ b1,
    const float* __restrict__ W2, const float* __restrict__ b2,
    const float* __restrict__ Wo, const float* __restrict__ bo,
    float* __restrict__ hA, float* __restrict__ normb,
    float* __restrict__ vbuf, float* __restrict__ cconst,
    float* __restrict__ acc, unsigned* __restrict__ ctr,
    unsigned short* __restrict__ WcT, float* __restrict__ b1c,
    unsigned short* __restrict__ protb)
{
    int t = threadIdx.x;
    int blk = blockIdx.x;
    const float* W1b = W1 + CG * HID;
    if (blk >= 513) {
        size_t base = (size_t)(blk - 513) * 2048 + (size_t)t * 8;
        float4 p0 = *(const float4*)(prot + base);
        float4 p1 = *(const float4*)(prot + base + 4);
        unsigned short o[8];
        o[0] = f2bf(p0.x); o[1] = f2bf(p0.y); o[2] = f2bf(p0.z); o[3] = f2bf(p0.w);
        o[4] = f2bf(p1.x); o[5] = f2bf(p1.y); o[6] = f2bf(p1.z); o[7] = f2bf(p1.w);
        *(short8*)(protb + base) = *(const short8*)o;
        return;
    }
    if (blk == 256) {
        if (t < HID) {
            float s = 0.f;
            for (int k = 0; k < CG; ++k) s = fmaf(W2[t * CG + k], Wo[k], s);
            vbuf[t] = s;
            float sb = 0.f;
            for (int m = 0; m < CG; ++m) sb = fmaf(br[m], W1b[m * HID + t], sb);
            b1c[t] = b1[t] + sb;
        }
        if (t == 255) {
            float s = 0.f;
            for (int k = 0; k < CG; ++k) s = fmaf(b2[k], Wo[k], s);
            cconst[0] = (float)(NN * LL) * s + bo[0];
        }
        if (t == 254) *ctr = 0u;
        if (t < BB) acc[t] = 0.f;
        return;
    }
    if (blk > 256) {
        int r0 = (blk - 257) * 4;
        __shared__ float sW[4][CG];
        if (t < 128) ((float4*)&sW[0][0])[t] = ((const float4*)(Wr + (size_t)r0 * CG))[t];
        __syncthreads();
        #pragma unroll
        for (int q = 0; q < 3; ++q) {
            int o = q * 256 + t;            // 0..767
            int r = o / HID, c = o % HID;
            float s = 0.f;
            for (int m = 0; m < CG; ++m) s = fmaf(sW[r][m], W1b[m * HID + c], s);
            WcT[(size_t)c * RD + r0 + r] = f2bf(s);
        }
        return;
    }
    int b = blk >> 5;           // 32 blocks per batch
    int n0 = (blk & 31) * 4;    // 4 rows per block
    __shared__ float sn[4][ND];
    sn[t >> 6][t & 63] = nodes[(b * NN + n0 + (t >> 6)) * ND + (t & 63)];
    __syncthreads();
    {
        int w = t >> 6, lane = t & 63;
        const float* ar = adj + (size_t)(b * NN + n0 + w) * NN;
        float d = ar[lane] + ar[lane + 64];
        for (int off = 32; off; off >>= 1) d += __shfl_down(d, off);
        if (lane == 0) normb[b * NN + n0 + w] = rsqrtf(fmaxf(d, 1.0f));
    }
    int c = t & 127, rr = t >> 7;   // rows rr and rr+2
    float a0 = bn[c], a1 = bn[c];
    for (int k = 0; k < ND; ++k) {
        float wv = Wn[k * CG + c];
        a0 = fmaf(sn[rr][k], wv, a0);
        a1 = fmaf(sn[rr + 2][k], wv, a1);
    }
    hA[(b * NN + n0 + rr) * CG + c] = a0;
    hA[(b * NN + n0 + rr + 2) * CG + c] = a1;
}

// ---------------------------------------------------------------------------
// K2: one GNN step: hnew = act( (adj @ (h*norm)) * norm @ Wg + bg )
// MODE 0: relu, store hout. MODE 1: tanh, then hW1 = h @ W1_top + b1c.
// grid B*32 (4 rows/block) x 512 threads (8 waves -> 2 waves/SIMD)
// ---------------------------------------------------------------------------
template <int MODE>
__global__ __launch_bounds__(512) void k2_gnn(
    const float* __restrict__ adj, const float* __restrict__ hin,
    const float* __restrict__ Wg, const float* __restrict__ bg,
    const float* __restrict__ normb, float* __restrict__ hout,
    const float* __restrict__ W1, const float* __restrict__ b1c,
    float* __restrict__ hW1)
{
    int t = threadIdx.x;
    int b = blockIdx.x >> 5;
    int i0 = (blockIdx.x & 31) * 4;
    __shared__ float hs[64][CG];    // 32KB
    __shared__ float ms[4][CG];
    int c = t & 127;
    int ib = t >> 7;                // 0..3 (one row per thread)
    float m = 0.f;
    const float* hbase = hin + (size_t)b * NN * CG;
    for (int half = 0; half < 2; ++half) {
        __syncthreads();
        #pragma unroll
        for (int q = 0; q < 4; ++q) {
            int f4 = t + 512 * q;        // 0..2047
            int row = f4 >> 5;           // 0..63
            int col4 = (f4 & 31) * 4;
            float4 hv = *(const float4*)(hbase + (half * 64 + row) * CG + col4);
            float nv = normb[b * NN + half * 64 + row];
            hv.x *= nv; hv.y *= nv; hv.z *= nv; hv.w *= nv;
            *(float4*)(&hs[row][col4]) = hv;
        }
        __syncthreads();
        const float* arow = adj + (size_t)(b * NN + i0 + ib) * NN + half * 64;
        for (int j = 0; j < 64; ++j)
            m = fmaf(arow[j], hs[j][c], m);
    }
    ms[ib][c] = m * normb[b * NN + i0 + ib];
    __syncthreads();
    float acc2 = bg[c];
    for (int k = 0; k < CG; ++k)
        acc2 = fmaf(ms[ib][k], Wg[k * CG + c], acc2);
    if (MODE == 0) {
        hout[(size_t)(b * NN + i0 + ib) * CG + c] = fmaxf(acc2, 0.f);
    } else {
        float* hn = &hs[0][0];   // reuse (4*128 floats)
        hn[ib * CG + c] = tanhf(acc2);
        __syncthreads();
        // hW1: 4 rows x 192 = 768 outputs; b1c (= b1 + br@W1b) folded here
        #pragma unroll
        for (int q = 0; q < 2; ++q) {
            int out = t + 512 * q;
            if (out < 4 * HID) {
                int i = out / HID, jj = out % HID;
                float s = b1c[jj];
                for (int k = 0; k < CG; ++k)
                    s = fmaf(hn[i * CG + k], W1[k * HID + jj], s);
                hW1[(size_t)(b * NN + i0 + i) * HID + jj] = s;
            }
        }
    }
}

// ---------------------------------------------------------------------------
// K3: partial rW1 = protb @ WcT^T over a K-half (512). No bias (in b1c).
// block = 256 thr (4 waves); wave owns 16 rows x 48 cols; grid 512 (2/SIMD)
// ---------------------------------------------------------------------------
__global__ __launch_bounds__(256) void k3_mfma(
    const unsigned short* __restrict__ protb, const unsigned short* __restrict__ WcT,
    float* __restrict__ rWp)
{
    int t = threadIdx.x;
    int w = t >> 6, l = t & 63;
    int kh = blockIdx.x & 1;
    int cb = (blockIdx.x >> 1) & 3;
    int rb = blockIdx.x >> 3;
    int r0 = rb * 64 + w * 16;
    int c0 = cb * 48;
    int lr = l & 15;
    int lk = (l >> 4) * 8;
    const unsigned short* ap = protb + (size_t)(r0 + lr) * RD + kh * 512 + lk;
    const unsigned short* bp = WcT + (size_t)(c0 + lr) * RD + kh * 512 + lk;
    f32x4 a0 = {0.f, 0.f, 0.f, 0.f}, a1 = a0, a2 = a0;
    #pragma unroll 4
    for (int k0 = 0; k0 < 512; k0 += 32) {
        short8 av = *(const short8*)(ap + k0);
        short8 b0 = *(const short8*)(bp + k0);
        short8 b1 = *(const short8*)(bp + 16 * RD + k0);
        short8 b2 = *(const short8*)(bp + 32 * RD + k0);
        a0 = __builtin_amdgcn_mfma_f32_16x16x32_bf16(av, b0, a0, 0, 0, 0);
        a1 = __builtin_amdgcn_mfma_f32_16x16x32_bf16(av, b1, a1, 0, 0, 0);
        a2 = __builtin_amdgcn_mfma_f32_16x16x32_bf16(av, b2, a2, 0, 0, 0);
    }
    int orow = r0 + (l >> 4) * 4;
    float* base = rWp + (size_t)kh * (4096 * HID);
    #pragma unroll
    for (int i = 0; i < 4; ++i) {
        float* cr = base + (size_t)(orow + i) * HID + c0 + lr;
        cr[0]  = a0[i];
        cr[16] = a1[i];
        cr[32] = a2[i];
    }
}

// ---------------------------------------------------------------------------
// K4: acc[b] += sum_{n,l} v . relu(hW1[b,n,:] + rWa[b,l,:] + rWb[b,l,:])
//     last block writes out[b] = acc[b] + cconst.
// grid B*8(nsplit)*8(ltile) = 512 x 256
// ---------------------------------------------------------------------------
__global__ __launch_bounds__(256) void k4_pairsum(
    const float* __restrict__ hW1, const float* __restrict__ rWa,
    const float* __restrict__ rWb,
    const float* __restrict__ vbuf, float* __restrict__ acc,
    const float* __restrict__ cconst, unsigned* __restrict__ ctr,
    float* __restrict__ out)
{
    int t = threadIdx.x;
    int blk = blockIdx.x;
    int b = blk >> 6;
    int ns = (blk >> 3) & 7;    // n range: 16 rows
    int lt = blk & 7;           // l tile: 64
    int wv = t >> 6;            // j-quarter (48 dims)
    int lane = t & 63;
    int j0 = wv * 48;
    int l = lt * 64 + lane;
    float r[48], v[48];
    const float* rpa = rWa + ((size_t)b * LL + l) * HID + j0;
    const float* rpb = rWb + ((size_t)b * LL + l) * HID + j0;
    const float* vp = vbuf + j0;
    #pragma unroll
    for (int q = 0; q < 12; ++q) {
        float4 f = *(const float4*)(rpa + q * 4);
        float4 g = *(const float4*)(rpb + q * 4);
        r[q * 4 + 0] = f.x + g.x; r[q * 4 + 1] = f.y + g.y;
        r[q * 4 + 2] = f.z + g.z; r[q * 4 + 3] = f.w + g.w;
    }
    #pragma unroll
    for (int q = 0; q < 12; ++q) {
        float4 f = *(const float4*)(vp + q * 4);
        v[q * 4 + 0] = f.x; v[q * 4 + 1] = f.y; v[q * 4 + 2] = f.z; v[q * 4 + 3] = f.w;
    }
    float a0 = 0.f, a1 = 0.f, a2 = 0.f, a3 = 0.f;
    const float* hp = hW1 + ((size_t)b * NN + ns * 16) * HID + j0;
    for (int n = 0; n < 16; ++n) {
        float hv[48];
        #pragma unroll
        for (int q = 0; q < 12; ++q) {
            float4 f = *(const float4*)(hp + n * HID + q * 4);
            hv[q * 4 + 0] = f.x; hv[q * 4 + 1] = f.y; hv[q * 4 + 2] = f.z; hv[q * 4 + 3] = f.w;
        }
        #pragma unroll
        for (int j = 0; j < 48; j += 4) {
            a0 = fmaf(v[j + 0], fmaxf(hv[j + 0] + r[j + 0], 0.f), a0);
            a1 = fmaf(v[j + 1], fmaxf(hv[j + 1] + r[j + 1], 0.f), a1);
            a2 = fmaf(v[j + 2], fmaxf(hv[j + 2] + r[j + 2], 0.f), a2);
            a3 = fmaf(v[j + 3], fmaxf(hv[j + 3] + r[j + 3], 0.f), a3);
        }
    }
    float a = (a0 + a1) + (a2 + a3);
    for (int off = 32; off; off >>= 1) a += __shfl_down(a, off);
    __shared__ float sred[4];
    __shared__ int lastf;
    if (lane == 0) sred[wv] = a;
    __syncthreads();
    if (t == 0) {
        atomicAdd(&acc[b], (sred[0] + sred[1]) + (sred[2] + sred[3]));
        __threadfence();
        unsigned old = atomicAdd(ctr, 1u);
        lastf = (old == gridDim.x - 1) ? 1 : 0;
    }
    __syncthreads();
    if (lastf && t < BB)
        out[t] = atomicAdd(&acc[t], 0.0f) + cconst[0];
}

extern "C" void kernel_launch(void* const* d_in, const int* in_sizes, int n_in,
                              void* d_out, int out_size, void* d_ws, size_t ws_size,
                              hipStream_t stream)
{
    const float* adj   = (const float*)d_in[0];
    const float* nodes = (const float*)d_in[1];
    const float* prot  = (const float*)d_in[2];
    const float* Wn    = (const float*)d_in[3];
    const float* bn    = (const float*)d_in[4];
    const float* Wg    = (const float*)d_in[5];
    const float* bg    = (const float*)d_in[6];
    const float* Wr    = (const float*)d_in[7];
    const float* br    = (const float*)d_in[8];
    // d_in[9]=Wa, d_in[10]=ba: unused (softmax over size-1 axis == 1)
    const float* W1    = (const float*)d_in[11];
    const float* b1    = (const float*)d_in[12];
    const float* W2    = (const float*)d_in[13];
    const float* b2    = (const float*)d_in[14];
    const float* Wo    = (const float*)d_in[15];
    const float* bo    = (const float*)d_in[16];

    float* ws     = (float*)d_ws;
    float* hA     = ws;                        // [8][128][128]
    float* hB     = ws + 131072;               // [8][128][128]
    float* normb  = ws + 262144;               // [8][128]
    float* hW1b   = ws + 263168;               // [8][128][192]
    float* rWa    = ws + 459776;               // [4096][192] K-half 0
    float* rWb    = ws + 1246208;              // [4096][192] K-half 1
    float* vbuf   = ws + 2032640;              // [192]
    float* cconst = ws + 2032832;              // [1]
    float* accb   = ws + 2032836;              // [8]
    float* b1c    = ws + 2032844;              // [192]
    unsigned* ctr = (unsigned*)(ws + 2033036); // [1]
    unsigned short* protb = (unsigned short*)(ws + 2033040); // [4096][1024] bf16
    unsigned short* WcT   = (unsigned short*)(ws + 4130192); // [192][1024] bf16
    float* out    = (float*)d_out;

    hipLaunchKernelGGL(k1_prep, dim3(2561), dim3(256), 0, stream,
                       adj, nodes, prot, Wn, bn, Wr, br, W1, b1, W2, b2, Wo, bo,
                       hA, normb, vbuf, cconst, accb, ctr, WcT, b1c, protb);
    hipLaunchKernelGGL(k3_mfma, dim3(512), dim3(256), 0, stream, protb, WcT, rWa);
    hipLaunchKernelGGL(k2_gnn<0>, dim3(BB * 32), dim3(512), 0, stream,
                       adj, hA, Wg, bg, normb, hB, W1, b1c, hW1b);
    hipLaunchKernelGGL(k2_gnn<0>, dim3(BB * 32), dim3(512), 0, stream,
                       adj, hB, Wg, bg, normb, hA, W1, b1c, hW1b);
    hipLaunchKernelGGL(k2_gnn<1>, dim3(BB * 32), dim3(512), 0, stream,
                       adj, hA, Wg, bg, normb, hB, W1, b1c, hW1b);
    hipLaunchKernelGGL(k4_pairsum, dim3(512), dim3(256), 0, stream,
                       hW1b, rWa, rWb, vbuf, accb, cconst, ctr, out);
}